// Round 1
// baseline (738.490 us; speedup 1.0000x reference)
//
#include <hip/hip_runtime.h>
#include <cstdint>
#include <cstddef>

// ---------- types ----------
typedef float  f32x4_t  __attribute__((ext_vector_type(4)));
typedef __bf16 bf16x8_t __attribute__((ext_vector_type(8)));
typedef __bf16 bf16x4_t __attribute__((ext_vector_type(4)));

#define NTOK   65536   // B*T*H*W = 4*16*32*32
#define CCH    256
#define NWINT  1024    // total windows (B*256)

// ---------- helpers ----------
__device__ __forceinline__ float wred_sum(float v) {
#pragma unroll
  for (int off = 32; off > 0; off >>= 1) v += __shfl_xor(v, off, 64);
  return v;
}

// async global->LDS, 16B per lane; lds must be wave-uniform (HW adds lane*16)
__device__ __forceinline__ void gload16(void* lds, const void* g) {
  __builtin_amdgcn_global_load_lds(
      (const __attribute__((address_space(1))) uint32_t*)g,
      (__attribute__((address_space(3))) uint32_t*)lds, 16, 0, 0);
}

// windowed-token -> original-token index (roll shift +2 both for gather at LN1
// and scatter at proj: rolled slot t holds/goes-to orig (t+2) mod dims)
__device__ __forceinline__ int win_to_orig(int token) {
  int gid = token >> 6, n = token & 63;
  int bb = gid >> 8, rem = gid & 255;
  int t = (((rem >> 6) << 2) + (n >> 4) + 2) & 15;
  int h = ((((rem >> 3) & 7) << 2) + ((n >> 2) & 3) + 2) & 31;
  int w = (((rem & 7) << 2) + (n & 3) + 2) & 31;
  return ((bb * 16 + t) * 32 + h) * 32 + w;
}

// ---------- weight transpose + bf16 convert ----------
// qkv_w (256,768) -> (768,256); proj_w (256,256) -> (256,256);
// mlp_w1 (256,1024) -> (1024,256); mlp_w2 (1024,256) -> (256,1024)
__global__ __launch_bounds__(256) void prep_weights(
    const float* __restrict__ qkv_w, const float* __restrict__ proj_w,
    const float* __restrict__ mlp_w1, const float* __restrict__ mlp_w2,
    __bf16* __restrict__ wt_qkv, __bf16* __restrict__ wt_proj,
    __bf16* __restrict__ wt_mlp1, __bf16* __restrict__ wt_mlp2) {
  int i = blockIdx.x * 256 + threadIdx.x;
  if (i < 196608) {
    int k = i / 768, n = i % 768;
    wt_qkv[n * 256 + k] = (__bf16)qkv_w[i];
  } else if (i < 262144) {
    int j = i - 196608;
    int k = j >> 8, n = j & 255;
    wt_proj[n * 256 + k] = (__bf16)proj_w[j];
  } else if (i < 524288) {
    int j = i - 262144;
    int k = j >> 10, n = j & 1023;
    wt_mlp1[n * 256 + k] = (__bf16)mlp_w1[j];
  } else {
    int j = i - 524288;
    int k = j >> 8, n = j & 255;
    wt_mlp2[n * 1024 + k] = (__bf16)mlp_w2[j];
  }
}

// ---------- LayerNorm (wave per token) ----------
// MODE 0: gather rolled+windowed source (LN1), MODE 1: identity rows (LN2)
template <int MODE>
__global__ __launch_bounds__(256) void ln_kernel(
    const float* __restrict__ xin, const float* __restrict__ g,
    const float* __restrict__ b, __bf16* __restrict__ out, float eps) {
  int token = blockIdx.x * 4 + (threadIdx.x >> 6);
  int lane = threadIdx.x & 63;
  size_t src = (MODE == 0) ? (size_t)win_to_orig(token) : (size_t)token;
  f32x4_t v = ((const f32x4_t*)(xin + src * CCH))[lane];
  float mu = wred_sum(v[0] + v[1] + v[2] + v[3]) * (1.0f / 256.0f);
  float d0 = v[0] - mu, d1 = v[1] - mu, d2 = v[2] - mu, d3 = v[3] - mu;
  float var = wred_sum(d0 * d0 + d1 * d1 + d2 * d2 + d3 * d3) * (1.0f / 256.0f);
  float rs = rsqrtf(var + eps);
  f32x4_t gg = ((const f32x4_t*)g)[lane];
  f32x4_t bb = ((const f32x4_t*)b)[lane];
  bf16x4_t o;
  o[0] = (__bf16)(d0 * rs * gg[0] + bb[0]);
  o[1] = (__bf16)(d1 * rs * gg[1] + bb[1]);
  o[2] = (__bf16)(d2 * rs * gg[2] + bb[2]);
  o[3] = (__bf16)(d3 * rs * gg[3] + bb[3]);
  *(bf16x4_t*)(out + (size_t)token * CCH + lane * 4) = o;
}

// ---------- GEMM: C = A(bf16 MxK) @ Bt(bf16 NxK)^T + bias, templated epilogue ----------
// EPI 0: bf16 store          EPI 1: scatter(window-reverse+roll) + x residual -> f32
// EPI 2: exact GELU -> bf16  EPI 3: + res -> f32
#define BM 128
#define BN 128
#define BK 64
template <int EPI>
__global__ __launch_bounds__(256) void gemm_kernel(
    const __bf16* __restrict__ A, const __bf16* __restrict__ Bt,
    const float* __restrict__ bias, const float* __restrict__ res,
    void* __restrict__ outp, int M, int N, int K) {
  __shared__ bf16x8_t smA[1024];  // 128 rows x 64 bf16 (8 x 16B chunks/row)
  __shared__ bf16x8_t smB[1024];
  const int wv = threadIdx.x >> 6;
  const int ln = threadIdx.x & 63;
  const int bm = blockIdx.y * BM;
  const int bn = blockIdx.x * BN;
  const int wr = wv >> 1, wc = wv & 1;

  f32x4_t acc[4][4];
#pragma unroll
  for (int m = 0; m < 4; ++m)
#pragma unroll
    for (int n = 0; n < 4; ++n) acc[m][n] = (f32x4_t){0.f, 0.f, 0.f, 0.f};

  const int KT = K >> 6;
  for (int kt = 0; kt < KT; ++kt) {
    // stage: linear LDS dest, pre-swizzled global source (chunk ^= row&7)
#pragma unroll
    for (int it = 0; it < 4; ++it) {
      int base = (it * 4 + wv) * 64;          // wave-uniform slot base
      int slot = base + ln;
      int row = slot >> 3;
      int chunk = (slot & 7) ^ (row & 7);
      gload16((void*)(smA + base),
              (const void*)(A + (size_t)(bm + row) * K + kt * BK + chunk * 8));
      gload16((void*)(smB + base),
              (const void*)(Bt + (size_t)(bn + row) * K + kt * BK + chunk * 8));
    }
    __syncthreads();  // drains vmcnt before reads

#pragma unroll
    for (int kh = 0; kh < 2; ++kh) {
      bf16x8_t af[4], bfr[4];
#pragma unroll
      for (int m = 0; m < 4; ++m) {
        int row = wr * 64 + m * 16 + (ln & 15);
        int c = (kh * 4 + (ln >> 4)) ^ (row & 7);
        af[m] = *(const bf16x8_t*)((const char*)smA + row * 128 + c * 16);
      }
#pragma unroll
      for (int n = 0; n < 4; ++n) {
        int row = wc * 64 + n * 16 + (ln & 15);
        int c = (kh * 4 + (ln >> 4)) ^ (row & 7);
        bfr[n] = *(const bf16x8_t*)((const char*)smB + row * 128 + c * 16);
      }
#pragma unroll
      for (int m = 0; m < 4; ++m)
#pragma unroll
        for (int n = 0; n < 4; ++n)
          acc[m][n] = __builtin_amdgcn_mfma_f32_16x16x32_bf16(
              af[m], bfr[n], acc[m][n], 0, 0, 0);
    }
    __syncthreads();  // before next stage overwrites LDS
  }

  // epilogue: C/D layout col=ln&15, row=(ln>>4)*4+reg
#pragma unroll
  for (int m = 0; m < 4; ++m) {
    int grow0 = bm + wr * 64 + m * 16 + ((ln >> 4) * 4);
#pragma unroll
    for (int n = 0; n < 4; ++n) {
      int gcol = bn + wc * 64 + n * 16 + (ln & 15);
      float bv = bias[gcol];
#pragma unroll
      for (int r = 0; r < 4; ++r) {
        int grow = grow0 + r;
        float v = acc[m][n][r] + bv;
        if constexpr (EPI == 0) {
          ((__bf16*)outp)[(size_t)grow * N + gcol] = (__bf16)v;
        } else if constexpr (EPI == 1) {
          size_t dst = (size_t)win_to_orig(grow) * CCH + gcol;
          ((float*)outp)[dst] = res[dst] + v;
        } else if constexpr (EPI == 2) {
          float gl = 0.5f * v * (1.0f + erff(v * 0.70710678118654752f));
          ((__bf16*)outp)[(size_t)grow * N + gcol] = (__bf16)gl;
        } else {
          size_t o = (size_t)grow * N + gcol;
          ((float*)outp)[o] = res[o] + v;
        }
      }
    }
  }
}

// ---------- windowed attention: 1 wave per (window, head) ----------
__global__ __launch_bounds__(64) void attn_kernel(
    const __bf16* __restrict__ qkv, const float* __restrict__ table,
    const int* __restrict__ ridx, const float* __restrict__ mask,
    __bf16* __restrict__ owin) {
  const int gid = blockIdx.x;  // window 0..1023
  const int hh = blockIdx.y;   // head 0..7
  const int i = threadIdx.x;   // row 0..63
  __shared__ __align__(16) float ks[64][32];
  __shared__ __align__(16) float vs[64][32];

  const __bf16* rowp = qkv + (size_t)(gid * 64 + i) * 768 + hh * 32;
  float q[32];
#pragma unroll
  for (int dq = 0; dq < 4; ++dq) {
    bf16x8_t qv = *(const bf16x8_t*)(rowp + dq * 8);
    bf16x8_t kv = *(const bf16x8_t*)(rowp + 256 + dq * 8);
    bf16x8_t vv = *(const bf16x8_t*)(rowp + 512 + dq * 8);
#pragma unroll
    for (int e = 0; e < 8; ++e) {
      q[dq * 8 + e] = (float)qv[e] * 0.17677669529663687f;  // hd^-0.5
      ks[i][dq * 8 + e] = (float)kv[e];
      vs[i][dq * 8 + e] = (float)vv[e];
    }
  }
  __syncthreads();

  const float* mrow = mask + (size_t)(gid & 255) * 4096 + i * 64;
  const int* rrow = ridx + i * 64;

  float s[64];
  float mx = -1e30f;
#pragma unroll
  for (int j = 0; j < 64; ++j) {
    const f32x4_t* kr = (const f32x4_t*)ks[j];
    float a = 0.f;
#pragma unroll
    for (int dq = 0; dq < 8; ++dq) {
      f32x4_t kk = kr[dq];
      a += q[dq * 4 + 0] * kk[0] + q[dq * 4 + 1] * kk[1] +
           q[dq * 4 + 2] * kk[2] + q[dq * 4 + 3] * kk[3];
    }
    a += table[rrow[j] * 8 + hh] + mrow[j];
    s[j] = a;
    mx = fmaxf(mx, a);
  }
  float sum = 0.f;
#pragma unroll
  for (int j = 0; j < 64; ++j) {
    s[j] = __expf(s[j] - mx);
    sum += s[j];
  }
  float inv = 1.0f / sum;
  float o[32];
#pragma unroll
  for (int d = 0; d < 32; ++d) o[d] = 0.f;
#pragma unroll
  for (int j = 0; j < 64; ++j) {
    const f32x4_t* vr = (const f32x4_t*)vs[j];
    float p = s[j];
#pragma unroll
    for (int dq = 0; dq < 8; ++dq) {
      f32x4_t vv = vr[dq];
      o[dq * 4 + 0] += p * vv[0];
      o[dq * 4 + 1] += p * vv[1];
      o[dq * 4 + 2] += p * vv[2];
      o[dq * 4 + 3] += p * vv[3];
    }
  }
  __bf16* op = owin + (size_t)(gid * 64 + i) * 256 + hh * 32;
#pragma unroll
  for (int dq = 0; dq < 4; ++dq) {
    bf16x8_t ov;
#pragma unroll
    for (int e = 0; e < 8; ++e) ov[e] = (__bf16)(o[dq * 8 + e] * inv);
    *(bf16x8_t*)(op + dq * 8) = ov;
  }
}

// ---------- launch ----------
extern "C" void kernel_launch(void* const* d_in, const int* in_sizes, int n_in,
                              void* d_out, int out_size, void* d_ws,
                              size_t ws_size, hipStream_t stream) {
  (void)in_sizes; (void)n_in; (void)out_size; (void)ws_size;
  const float* x      = (const float*)d_in[0];
  const float* n1g    = (const float*)d_in[1];
  const float* n1b    = (const float*)d_in[2];
  const float* qkv_w  = (const float*)d_in[3];
  const float* qkv_b  = (const float*)d_in[4];
  const float* proj_w = (const float*)d_in[5];
  const float* proj_b = (const float*)d_in[6];
  const float* rbt    = (const float*)d_in[7];
  const float* n2g    = (const float*)d_in[8];
  const float* n2b    = (const float*)d_in[9];
  const float* mlp_w1 = (const float*)d_in[10];
  const float* mlp_b1 = (const float*)d_in[11];
  const float* mlp_w2 = (const float*)d_in[12];
  const float* mlp_b2 = (const float*)d_in[13];
  const int*   ridx   = (const int*)d_in[14];
  const float* amask  = (const float*)d_in[15];

  char* ws = (char*)d_ws;
  size_t off = 0;
  auto alloc = [&](size_t bytes) {
    void* p = ws + off;
    off += (bytes + 255) & ~(size_t)255;
    return p;
  };
  __bf16* wt_qkv  = (__bf16*)alloc(768 * 256 * 2);
  __bf16* wt_proj = (__bf16*)alloc(256 * 256 * 2);
  __bf16* wt_mlp1 = (__bf16*)alloc(1024 * 256 * 2);
  __bf16* wt_mlp2 = (__bf16*)alloc(1024 * 256 * 2);
  __bf16* hwin = (__bf16*)alloc((size_t)NTOK * 256 * 2);  // LN1 out; later reused as y
  __bf16* qkv  = (__bf16*)alloc((size_t)NTOK * 768 * 2);  // qkv; later mlp hidden (with owin)
  __bf16* owin = (__bf16*)alloc((size_t)NTOK * 256 * 2);  // attn out (must follow qkv!)
  __bf16* yb   = hwin;
  __bf16* mlph = qkv;          // 128MB = qkv(96MB)+owin(32MB), contiguous
  float* x2    = (float*)d_out;  // residual-1 result lives in d_out

  prep_weights<<<3072, 256, 0, stream>>>(qkv_w, proj_w, mlp_w1, mlp_w2,
                                         wt_qkv, wt_proj, wt_mlp1, wt_mlp2);
  ln_kernel<0><<<NTOK / 4, 256, 0, stream>>>(x, n1g, n1b, hwin, 1e-5f);
  gemm_kernel<0><<<dim3(768 / BN, NTOK / BM), 256, 0, stream>>>(
      hwin, wt_qkv, qkv_b, nullptr, qkv, NTOK, 768, 256);
  attn_kernel<<<dim3(NWINT, 8), 64, 0, stream>>>(qkv, rbt, ridx, amask, owin);
  gemm_kernel<1><<<dim3(256 / BN, NTOK / BM), 256, 0, stream>>>(
      owin, wt_proj, proj_b, x, x2, NTOK, 256, 256);
  ln_kernel<1><<<NTOK / 4, 256, 0, stream>>>(x2, n2g, n2b, yb, 1e-6f);
  gemm_kernel<2><<<dim3(1024 / BN, NTOK / BM), 256, 0, stream>>>(
      yb, wt_mlp1, mlp_b1, nullptr, mlph, NTOK, 1024, 256);
  gemm_kernel<3><<<dim3(256 / BN, NTOK / BM), 256, 0, stream>>>(
      mlph, wt_mlp2, mlp_b2, x2, d_out, NTOK, 256, 1024);
}

// Round 2
// 361.906 us; speedup vs baseline: 2.0406x; 2.0406x over previous
//
#include <hip/hip_runtime.h>
#include <cstdint>
#include <cstddef>

// ---------- types ----------
typedef float  f32x4_t  __attribute__((ext_vector_type(4)));
typedef __bf16 bf16x8_t __attribute__((ext_vector_type(8)));
typedef __bf16 bf16x4_t __attribute__((ext_vector_type(4)));

#define NTOK   65536   // B*T*H*W = 4*16*32*32
#define CCH    256
#define NWINT  1024    // total windows (B*256)

// ---------- helpers ----------
__device__ __forceinline__ float wred_sum(float v) {
#pragma unroll
  for (int off = 32; off > 0; off >>= 1) v += __shfl_xor(v, off, 64);
  return v;
}

// async global->LDS, 16B per lane; lds dest must be wave-uniform (HW adds lane*16)
__device__ __forceinline__ void gload16(void* lds, const void* g) {
  __builtin_amdgcn_global_load_lds(
      (const __attribute__((address_space(1))) uint32_t*)g,
      (__attribute__((address_space(3))) uint32_t*)lds, 16, 0, 0);
}

// windowed-token -> original-token index (roll shift +2 both for gather at LN1
// and scatter at proj: rolled slot t holds/goes-to orig (t+2) mod dims)
__device__ __forceinline__ int win_to_orig(int token) {
  int gid = token >> 6, n = token & 63;
  int bb = gid >> 8, rem = gid & 255;
  int t = (((rem >> 6) << 2) + (n >> 4) + 2) & 15;
  int h = ((((rem >> 3) & 7) << 2) + ((n >> 2) & 3) + 2) & 31;
  int w = (((rem & 7) << 2) + (n & 3) + 2) & 31;
  return ((bb * 16 + t) * 32 + h) * 32 + w;
}

// ---------- weight transpose + bf16 convert ----------
__global__ __launch_bounds__(256) void prep_weights(
    const float* __restrict__ qkv_w, const float* __restrict__ proj_w,
    const float* __restrict__ mlp_w1, const float* __restrict__ mlp_w2,
    __bf16* __restrict__ wt_qkv, __bf16* __restrict__ wt_proj,
    __bf16* __restrict__ wt_mlp1, __bf16* __restrict__ wt_mlp2) {
  int i = blockIdx.x * 256 + threadIdx.x;
  if (i < 196608) {
    int k = i / 768, n = i % 768;
    wt_qkv[n * 256 + k] = (__bf16)qkv_w[i];
  } else if (i < 262144) {
    int j = i - 196608;
    int k = j >> 8, n = j & 255;
    wt_proj[n * 256 + k] = (__bf16)proj_w[j];
  } else if (i < 524288) {
    int j = i - 262144;
    int k = j >> 10, n = j & 1023;
    wt_mlp1[n * 256 + k] = (__bf16)mlp_w1[j];
  } else {
    int j = i - 524288;
    int k = j >> 8, n = j & 255;
    wt_mlp2[n * 1024 + k] = (__bf16)mlp_w2[j];
  }
}

// ---------- bias+mask precompute, fragment-ordered ----------
// cm[w][h][t16=jt*4+it][lane][r] = table[ridx[i][j]][h] + mask[w][i][j]
// with i = it*16 + (lane&15), j = jt*16 + (lane>>4)*4 + r
__global__ __launch_bounds__(256) void cm_prep(
    const float* __restrict__ table, const int* __restrict__ ridx,
    const float* __restrict__ mask, __bf16* __restrict__ cm) {
  int tid = blockIdx.x * 256 + threadIdx.x;  // 0 .. 2M-1
  int l = tid & 63;
  int t16 = (tid >> 6) & 15;
  int h = (tid >> 10) & 7;
  int w = tid >> 13;  // 0..255
  int it = t16 & 3, jt = t16 >> 2;
  int i = it * 16 + (l & 15);
  int jb = jt * 16 + ((l >> 4) << 2);
  const float* mrow = mask + (size_t)w * 4096 + i * 64;
  const int* rrow = ridx + i * 64;
  bf16x4_t o;
#pragma unroll
  for (int r = 0; r < 4; ++r) {
    int j = jb + r;
    o[r] = (__bf16)(table[rrow[j] * 8 + h] + mrow[j]);
  }
  *(bf16x4_t*)(cm + (size_t)tid * 4) = o;
}

// ---------- LayerNorm (wave per token) ----------
template <int MODE>
__global__ __launch_bounds__(256) void ln_kernel(
    const float* __restrict__ xin, const float* __restrict__ g,
    const float* __restrict__ b, __bf16* __restrict__ out, float eps) {
  int token = blockIdx.x * 4 + (threadIdx.x >> 6);
  int lane = threadIdx.x & 63;
  size_t src = (MODE == 0) ? (size_t)win_to_orig(token) : (size_t)token;
  f32x4_t v = ((const f32x4_t*)(xin + src * CCH))[lane];
  float mu = wred_sum(v[0] + v[1] + v[2] + v[3]) * (1.0f / 256.0f);
  float d0 = v[0] - mu, d1 = v[1] - mu, d2 = v[2] - mu, d3 = v[3] - mu;
  float var = wred_sum(d0 * d0 + d1 * d1 + d2 * d2 + d3 * d3) * (1.0f / 256.0f);
  float rs = rsqrtf(var + eps);
  f32x4_t gg = ((const f32x4_t*)g)[lane];
  f32x4_t bb = ((const f32x4_t*)b)[lane];
  bf16x4_t o;
  o[0] = (__bf16)(d0 * rs * gg[0] + bb[0]);
  o[1] = (__bf16)(d1 * rs * gg[1] + bb[1]);
  o[2] = (__bf16)(d2 * rs * gg[2] + bb[2]);
  o[3] = (__bf16)(d3 * rs * gg[3] + bb[3]);
  *(bf16x4_t*)(out + (size_t)token * CCH + lane * 4) = o;
}

// ---------- GEMM: C = A(bf16 MxK) @ Bt(bf16 NxK)^T + bias ----------
#define BM 128
#define BN 128
#define BK 64
template <int EPI>
__global__ __launch_bounds__(256) void gemm_kernel(
    const __bf16* __restrict__ A, const __bf16* __restrict__ Bt,
    const float* __restrict__ bias, const float* __restrict__ res,
    void* __restrict__ outp, int M, int N, int K) {
  __shared__ bf16x8_t smA[1024];  // 128 rows x 64 bf16
  __shared__ bf16x8_t smB[1024];
  const int wv = threadIdx.x >> 6;
  const int ln = threadIdx.x & 63;
  const int bm = blockIdx.y * BM;
  const int bn = blockIdx.x * BN;
  const int wr = wv >> 1, wc = wv & 1;

  f32x4_t acc[4][4];
#pragma unroll
  for (int m = 0; m < 4; ++m)
#pragma unroll
    for (int n = 0; n < 4; ++n) acc[m][n] = (f32x4_t){0.f, 0.f, 0.f, 0.f};

  const int KT = K >> 6;
  for (int kt = 0; kt < KT; ++kt) {
#pragma unroll
    for (int it = 0; it < 4; ++it) {
      int base = (it * 4 + wv) * 64;
      int slot = base + ln;
      int row = slot >> 3;
      int chunk = (slot & 7) ^ (row & 7);
      gload16((void*)(smA + base),
              (const void*)(A + (size_t)(bm + row) * K + kt * BK + chunk * 8));
      gload16((void*)(smB + base),
              (const void*)(Bt + (size_t)(bn + row) * K + kt * BK + chunk * 8));
    }
    __syncthreads();

#pragma unroll
    for (int kh = 0; kh < 2; ++kh) {
      bf16x8_t af[4], bfr[4];
#pragma unroll
      for (int m = 0; m < 4; ++m) {
        int row = wr * 64 + m * 16 + (ln & 15);
        int c = (kh * 4 + (ln >> 4)) ^ (row & 7);
        af[m] = *(const bf16x8_t*)((const char*)smA + row * 128 + c * 16);
      }
#pragma unroll
      for (int n = 0; n < 4; ++n) {
        int row = wc * 64 + n * 16 + (ln & 15);
        int c = (kh * 4 + (ln >> 4)) ^ (row & 7);
        bfr[n] = *(const bf16x8_t*)((const char*)smB + row * 128 + c * 16);
      }
#pragma unroll
      for (int m = 0; m < 4; ++m)
#pragma unroll
        for (int n = 0; n < 4; ++n)
          acc[m][n] = __builtin_amdgcn_mfma_f32_16x16x32_bf16(
              af[m], bfr[n], acc[m][n], 0, 0, 0);
    }
    __syncthreads();
  }

#pragma unroll
  for (int m = 0; m < 4; ++m) {
    int grow0 = bm + wr * 64 + m * 16 + ((ln >> 4) * 4);
#pragma unroll
    for (int n = 0; n < 4; ++n) {
      int gcol = bn + wc * 64 + n * 16 + (ln & 15);
      float bv = bias[gcol];
#pragma unroll
      for (int r = 0; r < 4; ++r) {
        int grow = grow0 + r;
        float v = acc[m][n][r] + bv;
        if constexpr (EPI == 0) {
          ((__bf16*)outp)[(size_t)grow * N + gcol] = (__bf16)v;
        } else if constexpr (EPI == 1) {
          size_t dst = (size_t)win_to_orig(grow) * CCH + gcol;
          ((float*)outp)[dst] = res[dst] + v;
        } else if constexpr (EPI == 2) {
          float gl = 0.5f * v * (1.0f + erff(v * 0.70710678118654752f));
          ((__bf16*)outp)[(size_t)grow * N + gcol] = (__bf16)gl;
        } else {
          size_t o = (size_t)grow * N + gcol;
          ((float*)outp)[o] = res[o] + v;
        }
      }
    }
  }
}

// ---------- MFMA windowed attention: 1 wave per (window, head) ----------
// S^T = mfma(K,Q) so softmax j-reduction is in-register + 2 shuffles.
__global__ __launch_bounds__(256) void attn_mfma(
    const __bf16* __restrict__ qkv, const __bf16* __restrict__ cm,
    __bf16* __restrict__ owin) {
  __shared__ __align__(16) __bf16 smP[4][64 * 72];  // P, padded stride 72
  __shared__ __align__(16) __bf16 smV[4][64 * 32];  // V, linear rows
  const int wv = threadIdx.x >> 6;
  const int ln = threadIdx.x & 63;
  const int task = blockIdx.x * 4 + wv;  // 0..8191
  const int win = task >> 3;
  const int h = task & 7;
  const int i15 = ln & 15, g = ln >> 4;

  const __bf16* base = qkv + (size_t)win * 64 * 768 + h * 32;

  // stage V (rows j, 32 d) -> LDS linear, async; dest base wave-uniform
  {
    __bf16* vdst = smV[wv];
#pragma unroll
    for (int c = 0; c < 4; ++c) {
      const __bf16* src =
          base + (size_t)(c * 16 + (ln >> 2)) * 768 + 512 + (ln & 3) * 8;
      gload16(vdst + c * 512, src);
    }
  }

  // K/Q fragments straight from global: row (t*16 + i15), d-chunk g*8
  bf16x8_t kf[4], qf[4];
#pragma unroll
  for (int t = 0; t < 4; ++t) {
    kf[t] = *(const bf16x8_t*)(base + (size_t)(t * 16 + i15) * 768 + 256 + g * 8);
    qf[t] = *(const bf16x8_t*)(base + (size_t)(t * 16 + i15) * 768 + g * 8);
  }

  // S^T tiles: st[jt][it], rows j, cols i
  f32x4_t st[4][4];
#pragma unroll
  for (int jt = 0; jt < 4; ++jt)
#pragma unroll
    for (int it = 0; it < 4; ++it)
      st[jt][it] = __builtin_amdgcn_mfma_f32_16x16x32_bf16(
          kf[jt], qf[it], (f32x4_t){0.f, 0.f, 0.f, 0.f}, 0, 0, 0);

  // scale + bias + mask (fragment-ordered cm)
  const __bf16* cmp = cm + (((size_t)(win & 255) * 8 + h) * 16) * 256;
#pragma unroll
  for (int jt = 0; jt < 4; ++jt)
#pragma unroll
    for (int it = 0; it < 4; ++it) {
      bf16x4_t c4 = *(const bf16x4_t*)(cmp + ((jt * 4 + it) * 64 + ln) * 4);
#pragma unroll
      for (int r = 0; r < 4; ++r)
        st[jt][it][r] =
            fmaf(st[jt][it][r], 0.17677669529663687f, (float)c4[r]);
    }

  // softmax over j per column i (i = it*16 + i15); j spans regs + lane-groups
#pragma unroll
  for (int it = 0; it < 4; ++it) {
    float mx = -1e30f;
#pragma unroll
    for (int jt = 0; jt < 4; ++jt)
#pragma unroll
      for (int r = 0; r < 4; ++r) mx = fmaxf(mx, st[jt][it][r]);
    mx = fmaxf(mx, __shfl_xor(mx, 16, 64));
    mx = fmaxf(mx, __shfl_xor(mx, 32, 64));
    float sum = 0.f;
#pragma unroll
    for (int jt = 0; jt < 4; ++jt)
#pragma unroll
      for (int r = 0; r < 4; ++r) {
        float p = __expf(st[jt][it][r] - mx);
        st[jt][it][r] = p;
        sum += p;
      }
    sum += __shfl_xor(sum, 16, 64);
    sum += __shfl_xor(sum, 32, 64);
    float inv = 1.0f / sum;
    // write P row i = it*16+i15, cols jt*16 + g*4 + r (8B, 2-way banks)
#pragma unroll
    for (int jt = 0; jt < 4; ++jt) {
      bf16x4_t p4;
#pragma unroll
      for (int r = 0; r < 4; ++r) p4[r] = (__bf16)(st[jt][it][r] * inv);
      *(bf16x4_t*)(smP[wv] + (it * 16 + i15) * 72 + jt * 16 + g * 4) = p4;
    }
  }
  __syncthreads();  // drain V gload (vmcnt) + P writes (lgkm)

  // O = P @ V : A = P (row i, k j), B = V (col d, k j)
  f32x4_t oacc[4][2];
#pragma unroll
  for (int it = 0; it < 4; ++it)
#pragma unroll
    for (int dt = 0; dt < 2; ++dt) oacc[it][dt] = (f32x4_t){0.f, 0.f, 0.f, 0.f};

  const __bf16* pl = smP[wv];
  const __bf16* vl = smV[wv];
#pragma unroll
  for (int kt = 0; kt < 2; ++kt) {
    bf16x8_t vf[2];
#pragma unroll
    for (int dt = 0; dt < 2; ++dt)
#pragma unroll
      for (int e = 0; e < 8; ++e)
        vf[dt][e] = vl[(kt * 32 + g * 8 + e) * 32 + dt * 16 + i15];
#pragma unroll
    for (int it = 0; it < 4; ++it) {
      bf16x8_t pa =
          *(const bf16x8_t*)(pl + (it * 16 + i15) * 72 + kt * 32 + g * 8);
#pragma unroll
      for (int dt = 0; dt < 2; ++dt)
        oacc[it][dt] = __builtin_amdgcn_mfma_f32_16x16x32_bf16(
            pa, vf[dt], oacc[it][dt], 0, 0, 0);
    }
  }

  // store O: row i = it*16 + 4g + r, col d = dt*16 + i15
  __bf16* op = owin + (size_t)win * 64 * 256 + h * 32;
#pragma unroll
  for (int it = 0; it < 4; ++it)
#pragma unroll
    for (int r = 0; r < 4; ++r) {
      int i = it * 16 + g * 4 + r;
#pragma unroll
      for (int dt = 0; dt < 2; ++dt)
        op[(size_t)i * 256 + dt * 16 + i15] = (__bf16)oacc[it][dt][r];
    }
}

// ---------- launch ----------
extern "C" void kernel_launch(void* const* d_in, const int* in_sizes, int n_in,
                              void* d_out, int out_size, void* d_ws,
                              size_t ws_size, hipStream_t stream) {
  (void)in_sizes; (void)n_in; (void)out_size; (void)ws_size;
  const float* x      = (const float*)d_in[0];
  const float* n1g    = (const float*)d_in[1];
  const float* n1b    = (const float*)d_in[2];
  const float* qkv_w  = (const float*)d_in[3];
  const float* qkv_b  = (const float*)d_in[4];
  const float* proj_w = (const float*)d_in[5];
  const float* proj_b = (const float*)d_in[6];
  const float* rbt    = (const float*)d_in[7];
  const float* n2g    = (const float*)d_in[8];
  const float* n2b    = (const float*)d_in[9];
  const float* mlp_w1 = (const float*)d_in[10];
  const float* mlp_b1 = (const float*)d_in[11];
  const float* mlp_w2 = (const float*)d_in[12];
  const float* mlp_b2 = (const float*)d_in[13];
  const int*   ridx   = (const int*)d_in[14];
  const float* amask  = (const float*)d_in[15];

  char* ws = (char*)d_ws;
  size_t off = 0;
  auto alloc = [&](size_t bytes) {
    void* p = ws + off;
    off += (bytes + 255) & ~(size_t)255;
    return p;
  };
  __bf16* wt_qkv  = (__bf16*)alloc(768 * 256 * 2);
  __bf16* wt_proj = (__bf16*)alloc(256 * 256 * 2);
  __bf16* wt_mlp1 = (__bf16*)alloc(1024 * 256 * 2);
  __bf16* wt_mlp2 = (__bf16*)alloc(1024 * 256 * 2);
  __bf16* hwin = (__bf16*)alloc((size_t)NTOK * 256 * 2);  // LN1 out; reused: cm, then y
  __bf16* qkv  = (__bf16*)alloc((size_t)NTOK * 768 * 2);  // qkv; later mlp hidden
  __bf16* owin = (__bf16*)alloc((size_t)NTOK * 256 * 2);  // attn out (follows qkv)
  __bf16* cmb  = hwin;   // 16MB cm aliases hwin (dead after QKV GEMM)
  __bf16* yb   = hwin;   // LN2 out (after attn, cm dead)
  __bf16* mlph = qkv;    // 128MB contiguous (qkv+owin)
  float* x2    = (float*)d_out;

  prep_weights<<<3072, 256, 0, stream>>>(qkv_w, proj_w, mlp_w1, mlp_w2,
                                         wt_qkv, wt_proj, wt_mlp1, wt_mlp2);
  ln_kernel<0><<<NTOK / 4, 256, 0, stream>>>(x, n1g, n1b, hwin, 1e-5f);
  gemm_kernel<0><<<dim3(768 / BN, NTOK / BM), 256, 0, stream>>>(
      hwin, wt_qkv, qkv_b, nullptr, qkv, NTOK, 768, 256);
  cm_prep<<<8192, 256, 0, stream>>>(rbt, ridx, amask, cmb);
  attn_mfma<<<2048, 256, 0, stream>>>(qkv, cmb, owin);
  gemm_kernel<1><<<dim3(256 / BN, NTOK / BM), 256, 0, stream>>>(
      owin, wt_proj, proj_b, x, x2, NTOK, 256, 256);
  ln_kernel<1><<<NTOK / 4, 256, 0, stream>>>(x2, n2g, n2b, yb, 1e-6f);
  gemm_kernel<2><<<dim3(1024 / BN, NTOK / BM), 256, 0, stream>>>(
      yb, wt_mlp1, mlp_b1, nullptr, mlph, NTOK, 1024, 256);
  gemm_kernel<3><<<dim3(256 / BN, NTOK / BM), 256, 0, stream>>>(
      mlph, wt_mlp2, mlp_b2, x2, d_out, NTOK, 256, 1024);
}

// Round 3
// 359.835 us; speedup vs baseline: 2.0523x; 1.0058x over previous
//
#include <hip/hip_runtime.h>
#include <cstdint>
#include <cstddef>

// ---------- types ----------
typedef float  f32x4_t  __attribute__((ext_vector_type(4)));
typedef __bf16 bf16x8_t __attribute__((ext_vector_type(8)));
typedef __bf16 bf16x4_t __attribute__((ext_vector_type(4)));

#define NTOK   65536   // B*T*H*W = 4*16*32*32
#define CCH    256
#define NWINT  1024    // total windows (B*256)

// ---------- helpers ----------
__device__ __forceinline__ float wred_sum(float v) {
#pragma unroll
  for (int off = 32; off > 0; off >>= 1) v += __shfl_xor(v, off, 64);
  return v;
}

// async global->LDS, 16B per lane; lds dest must be wave-uniform (HW adds lane*16)
__device__ __forceinline__ void gload16(void* lds, const void* g) {
  __builtin_amdgcn_global_load_lds(
      (const __attribute__((address_space(1))) uint32_t*)g,
      (__attribute__((address_space(3))) uint32_t*)lds, 16, 0, 0);
}

// windowed-token -> original-token index (roll shift +2 both directions)
__device__ __forceinline__ int win_to_orig(int token) {
  int gid = token >> 6, n = token & 63;
  int bb = gid >> 8, rem = gid & 255;
  int t = (((rem >> 6) << 2) + (n >> 4) + 2) & 15;
  int h = ((((rem >> 3) & 7) << 2) + ((n >> 2) & 3) + 2) & 31;
  int w = (((rem & 7) << 2) + (n & 3) + 2) & 31;
  return ((bb * 16 + t) * 32 + h) * 32 + w;
}

// ---------- weight transpose + bf16 convert ----------
__global__ __launch_bounds__(256) void prep_weights(
    const float* __restrict__ qkv_w, const float* __restrict__ proj_w,
    const float* __restrict__ mlp_w1, const float* __restrict__ mlp_w2,
    __bf16* __restrict__ wt_qkv, __bf16* __restrict__ wt_proj,
    __bf16* __restrict__ wt_mlp1, __bf16* __restrict__ wt_mlp2) {
  int i = blockIdx.x * 256 + threadIdx.x;
  if (i < 196608) {
    int k = i / 768, n = i % 768;
    wt_qkv[n * 256 + k] = (__bf16)qkv_w[i];
  } else if (i < 262144) {
    int j = i - 196608;
    int k = j >> 8, n = j & 255;
    wt_proj[n * 256 + k] = (__bf16)proj_w[j];
  } else if (i < 524288) {
    int j = i - 262144;
    int k = j >> 10, n = j & 1023;
    wt_mlp1[n * 256 + k] = (__bf16)mlp_w1[j];
  } else {
    int j = i - 524288;
    int k = j >> 8, n = j & 255;
    wt_mlp2[n * 1024 + k] = (__bf16)mlp_w2[j];
  }
}

// ---------- bias+mask precompute, fragment-ordered ----------
__global__ __launch_bounds__(256) void cm_prep(
    const float* __restrict__ table, const int* __restrict__ ridx,
    const float* __restrict__ mask, __bf16* __restrict__ cm) {
  int tid = blockIdx.x * 256 + threadIdx.x;  // 0 .. 2M-1
  int l = tid & 63;
  int t16 = (tid >> 6) & 15;
  int h = (tid >> 10) & 7;
  int w = tid >> 13;  // 0..255
  int it = t16 & 3, jt = t16 >> 2;
  int i = it * 16 + (l & 15);
  int jb = jt * 16 + ((l >> 4) << 2);
  const float* mrow = mask + (size_t)w * 4096 + i * 64;
  const int* rrow = ridx + i * 64;
  bf16x4_t o;
#pragma unroll
  for (int r = 0; r < 4; ++r) {
    int j = jb + r;
    o[r] = (__bf16)(table[rrow[j] * 8 + h] + mrow[j]);
  }
  *(bf16x4_t*)(cm + (size_t)tid * 4) = o;
}

// ---------- LayerNorm (wave per token) ----------
template <int MODE>
__global__ __launch_bounds__(256) void ln_kernel(
    const float* __restrict__ xin, const float* __restrict__ g,
    const float* __restrict__ b, __bf16* __restrict__ out, float eps) {
  int token = blockIdx.x * 4 + (threadIdx.x >> 6);
  int lane = threadIdx.x & 63;
  size_t src = (MODE == 0) ? (size_t)win_to_orig(token) : (size_t)token;
  f32x4_t v = ((const f32x4_t*)(xin + src * CCH))[lane];
  float mu = wred_sum(v[0] + v[1] + v[2] + v[3]) * (1.0f / 256.0f);
  float d0 = v[0] - mu, d1 = v[1] - mu, d2 = v[2] - mu, d3 = v[3] - mu;
  float var = wred_sum(d0 * d0 + d1 * d1 + d2 * d2 + d3 * d3) * (1.0f / 256.0f);
  float rs = rsqrtf(var + eps);
  f32x4_t gg = ((const f32x4_t*)g)[lane];
  f32x4_t bb = ((const f32x4_t*)b)[lane];
  bf16x4_t o;
  o[0] = (__bf16)(d0 * rs * gg[0] + bb[0]);
  o[1] = (__bf16)(d1 * rs * gg[1] + bb[1]);
  o[2] = (__bf16)(d2 * rs * gg[2] + bb[2]);
  o[3] = (__bf16)(d3 * rs * gg[3] + bb[3]);
  *(bf16x4_t*)(out + (size_t)token * CCH + lane * 4) = o;
}

// ---------- GEMM: C = A(bf16 MxK) @ Bt(bf16 NxK)^T + bias ----------
// double-buffered LDS, counted vmcnt, hoisted addresses, XCD-chunked swizzle
#define BM 128
#define BN 128
#define BK 64
template <int EPI>
__global__ __launch_bounds__(256) void gemm_kernel(
    const __bf16* __restrict__ A, const __bf16* __restrict__ Bt,
    const float* __restrict__ bias, const float* __restrict__ res,
    void* __restrict__ outp, int M, int N, int K) {
  __shared__ __bf16 smA[2][8192];  // [buf][128 rows x 64], row stride 64
  __shared__ __bf16 smB[2][8192];
  const int wv = threadIdx.x >> 6;
  const int ln = threadIdx.x & 63;
  const int i15 = ln & 15, g = ln >> 4;

  // bijective XCD-chunked swizzle (all grids here are %8==0)
  int nwg = gridDim.x;
  int wgid = ((int)blockIdx.x & 7) * (nwg >> 3) + ((int)blockIdx.x >> 3);
  int nx = N >> 7;
  int bx = wgid % nx, by = wgid / nx;
  const int bm = by * BM, bn = bx * BN;
  const int wr = wv >> 1, wc = wv & 1;

  // per-lane staging pointers (computed once, bumped per tile)
  const __bf16* aP[4];
  const __bf16* bP[4];
#pragma unroll
  for (int it = 0; it < 4; ++it) {
    int slot = (it * 4 + wv) * 64 + ln;
    int row = slot >> 3;
    int chunk = (slot & 7) ^ (row & 7);
    aP[it] = A + (size_t)(bm + row) * K + chunk * 8;
    bP[it] = Bt + (size_t)(bn + row) * K + chunk * 8;
  }

  f32x4_t acc[4][4];
#pragma unroll
  for (int m = 0; m < 4; ++m)
#pragma unroll
    for (int n = 0; n < 4; ++n) acc[m][n] = (f32x4_t){0.f, 0.f, 0.f, 0.f};

  const int KT = K >> 6;

  auto stage = [&](int buf) {
#pragma unroll
    for (int it = 0; it < 4; ++it) {
      int base = (it * 4 + wv) * 512;  // element offset of the wave's slice
      gload16(&smA[buf][base], aP[it]);
      gload16(&smB[buf][base], bP[it]);
      aP[it] += BK;
      bP[it] += BK;
    }
  };

  auto compute = [&](int buf) {
    const __bf16* lA = smA[buf];
    const __bf16* lB = smB[buf];
#pragma unroll
    for (int kh = 0; kh < 2; ++kh) {
      int cA = (((kh * 4) + g) ^ (i15 & 7)) * 8;
      bf16x8_t af[4], bfr[4];
#pragma unroll
      for (int m = 0; m < 4; ++m)
        af[m] = *(const bf16x8_t*)(lA + (wr * 64 + m * 16 + i15) * 64 + cA);
#pragma unroll
      for (int n = 0; n < 4; ++n)
        bfr[n] = *(const bf16x8_t*)(lB + (wc * 64 + n * 16 + i15) * 64 + cA);
#pragma unroll
      for (int m = 0; m < 4; ++m)
#pragma unroll
        for (int n = 0; n < 4; ++n)
          acc[m][n] = __builtin_amdgcn_mfma_f32_16x16x32_bf16(
              af[m], bfr[n], acc[m][n], 0, 0, 0);
    }
  };

  stage(0);
  for (int kt = 0; kt < KT - 1; ++kt) {
    stage((kt + 1) & 1);                               // prefetch next tile
    asm volatile("s_waitcnt vmcnt(8)" ::: "memory");   // cur tile landed
    __builtin_amdgcn_s_barrier();
    asm volatile("" ::: "memory");
    compute(kt & 1);
    asm volatile("s_waitcnt lgkmcnt(0)" ::: "memory"); // reads done pre-barrier
    __builtin_amdgcn_s_barrier();
  }
  asm volatile("s_waitcnt vmcnt(0)" ::: "memory");
  __builtin_amdgcn_s_barrier();
  asm volatile("" ::: "memory");
  compute((KT - 1) & 1);

  // epilogue: C/D layout col=ln&15, row=(ln>>4)*4+reg
  float bv[4];
#pragma unroll
  for (int n = 0; n < 4; ++n) bv[n] = bias[bn + wc * 64 + n * 16 + i15];
#pragma unroll
  for (int m = 0; m < 4; ++m) {
    int grow0 = bm + wr * 64 + m * 16 + g * 4;
#pragma unroll
    for (int r = 0; r < 4; ++r) {
      int grow = grow0 + r;
      size_t rowbase;
      if constexpr (EPI == 1)
        rowbase = (size_t)win_to_orig(grow) * CCH;
      else
        rowbase = (size_t)grow * N;
#pragma unroll
      for (int n = 0; n < 4; ++n) {
        int gcol = bn + wc * 64 + n * 16 + i15;
        float v = acc[m][n][r] + bv[n];
        if constexpr (EPI == 0) {
          ((__bf16*)outp)[rowbase + gcol] = (__bf16)v;
        } else if constexpr (EPI == 1) {
          size_t dst = rowbase + gcol;
          ((float*)outp)[dst] = res[dst] + v;
        } else if constexpr (EPI == 2) {
          float gl = 0.5f * v * (1.0f + erff(v * 0.70710678118654752f));
          ((__bf16*)outp)[rowbase + gcol] = (__bf16)gl;
        } else {
          size_t o = rowbase + gcol;
          ((float*)outp)[o] = res[o] + v;
        }
      }
    }
  }
}

// ---------- MFMA windowed attention: 1 wave per (window, head) ----------
__global__ __launch_bounds__(256) void attn_mfma(
    const __bf16* __restrict__ qkv, const __bf16* __restrict__ cm,
    __bf16* __restrict__ owin) {
  __shared__ __align__(16) __bf16 smP[4][64 * 72];  // P, padded stride 72
  __shared__ __align__(16) __bf16 smV[4][64 * 32];  // V, linear rows
  const int wv = threadIdx.x >> 6;
  const int ln = threadIdx.x & 63;
  const int task = blockIdx.x * 4 + wv;  // 0..8191
  const int win = task >> 3;
  const int h = task & 7;
  const int i15 = ln & 15, g = ln >> 4;

  const __bf16* base = qkv + (size_t)win * 64 * 768 + h * 32;

  // stage V (rows j, 32 d) -> LDS linear, async
  {
    __bf16* vdst = smV[wv];
#pragma unroll
    for (int c = 0; c < 4; ++c) {
      const __bf16* src =
          base + (size_t)(c * 16 + (ln >> 2)) * 768 + 512 + (ln & 3) * 8;
      gload16(vdst + c * 512, src);
    }
  }

  // K/Q fragments straight from global
  bf16x8_t kf[4], qf[4];
#pragma unroll
  for (int t = 0; t < 4; ++t) {
    kf[t] = *(const bf16x8_t*)(base + (size_t)(t * 16 + i15) * 768 + 256 + g * 8);
    qf[t] = *(const bf16x8_t*)(base + (size_t)(t * 16 + i15) * 768 + g * 8);
  }

  // S^T tiles: st[jt][it], rows j, cols i
  f32x4_t st[4][4];
#pragma unroll
  for (int jt = 0; jt < 4; ++jt)
#pragma unroll
    for (int it = 0; it < 4; ++it)
      st[jt][it] = __builtin_amdgcn_mfma_f32_16x16x32_bf16(
          kf[jt], qf[it], (f32x4_t){0.f, 0.f, 0.f, 0.f}, 0, 0, 0);

  // scale + bias + mask (fragment-ordered cm)
  const __bf16* cmp = cm + (((size_t)(win & 255) * 8 + h) * 16) * 256;
#pragma unroll
  for (int jt = 0; jt < 4; ++jt)
#pragma unroll
    for (int it = 0; it < 4; ++it) {
      bf16x4_t c4 = *(const bf16x4_t*)(cmp + ((jt * 4 + it) * 64 + ln) * 4);
#pragma unroll
      for (int r = 0; r < 4; ++r)
        st[jt][it][r] =
            fmaf(st[jt][it][r], 0.17677669529663687f, (float)c4[r]);
    }

  // softmax over j per column i
#pragma unroll
  for (int it = 0; it < 4; ++it) {
    float mx = -1e30f;
#pragma unroll
    for (int jt = 0; jt < 4; ++jt)
#pragma unroll
      for (int r = 0; r < 4; ++r) mx = fmaxf(mx, st[jt][it][r]);
    mx = fmaxf(mx, __shfl_xor(mx, 16, 64));
    mx = fmaxf(mx, __shfl_xor(mx, 32, 64));
    float sum = 0.f;
#pragma unroll
    for (int jt = 0; jt < 4; ++jt)
#pragma unroll
      for (int r = 0; r < 4; ++r) {
        float p = __expf(st[jt][it][r] - mx);
        st[jt][it][r] = p;
        sum += p;
      }
    sum += __shfl_xor(sum, 16, 64);
    sum += __shfl_xor(sum, 32, 64);
    float inv = 1.0f / sum;
#pragma unroll
    for (int jt = 0; jt < 4; ++jt) {
      bf16x4_t p4;
#pragma unroll
      for (int r = 0; r < 4; ++r) p4[r] = (__bf16)(st[jt][it][r] * inv);
      *(bf16x4_t*)(smP[wv] + (it * 16 + i15) * 72 + jt * 16 + g * 4) = p4;
    }
  }
  __syncthreads();  // drain V gload (vmcnt) + P writes (lgkm)

  // O = P @ V
  f32x4_t oacc[4][2];
#pragma unroll
  for (int it = 0; it < 4; ++it)
#pragma unroll
    for (int dt = 0; dt < 2; ++dt) oacc[it][dt] = (f32x4_t){0.f, 0.f, 0.f, 0.f};

  const __bf16* pl = smP[wv];
  const __bf16* vl = smV[wv];
#pragma unroll
  for (int kt = 0; kt < 2; ++kt) {
    bf16x8_t vf[2];
#pragma unroll
    for (int dt = 0; dt < 2; ++dt)
#pragma unroll
      for (int e = 0; e < 8; ++e)
        vf[dt][e] = vl[(kt * 32 + g * 8 + e) * 32 + dt * 16 + i15];
#pragma unroll
    for (int it = 0; it < 4; ++it) {
      bf16x8_t pa =
          *(const bf16x8_t*)(pl + (it * 16 + i15) * 72 + kt * 32 + g * 8);
#pragma unroll
      for (int dt = 0; dt < 2; ++dt)
        oacc[it][dt] = __builtin_amdgcn_mfma_f32_16x16x32_bf16(
            pa, vf[dt], oacc[it][dt], 0, 0, 0);
    }
  }

  __bf16* op = owin + (size_t)win * 64 * 256 + h * 32;
#pragma unroll
  for (int it = 0; it < 4; ++it)
#pragma unroll
    for (int r = 0; r < 4; ++r) {
      int i = it * 16 + g * 4 + r;
#pragma unroll
      for (int dt = 0; dt < 2; ++dt)
        op[(size_t)i * 256 + dt * 16 + i15] = (__bf16)oacc[it][dt][r];
    }
}

// ---------- launch ----------
extern "C" void kernel_launch(void* const* d_in, const int* in_sizes, int n_in,
                              void* d_out, int out_size, void* d_ws,
                              size_t ws_size, hipStream_t stream) {
  (void)in_sizes; (void)n_in; (void)out_size; (void)ws_size;
  const float* x      = (const float*)d_in[0];
  const float* n1g    = (const float*)d_in[1];
  const float* n1b    = (const float*)d_in[2];
  const float* qkv_w  = (const float*)d_in[3];
  const float* qkv_b  = (const float*)d_in[4];
  const float* proj_w = (const float*)d_in[5];
  const float* proj_b = (const float*)d_in[6];
  const float* rbt    = (const float*)d_in[7];
  const float* n2g    = (const float*)d_in[8];
  const float* n2b    = (const float*)d_in[9];
  const float* mlp_w1 = (const float*)d_in[10];
  const float* mlp_b1 = (const float*)d_in[11];
  const float* mlp_w2 = (const float*)d_in[12];
  const float* mlp_b2 = (const float*)d_in[13];
  const int*   ridx   = (const int*)d_in[14];
  const float* amask  = (const float*)d_in[15];

  char* ws = (char*)d_ws;
  size_t off = 0;
  auto alloc = [&](size_t bytes) {
    void* p = ws + off;
    off += (bytes + 255) & ~(size_t)255;
    return p;
  };
  __bf16* wt_qkv  = (__bf16*)alloc(768 * 256 * 2);
  __bf16* wt_proj = (__bf16*)alloc(256 * 256 * 2);
  __bf16* wt_mlp1 = (__bf16*)alloc(1024 * 256 * 2);
  __bf16* wt_mlp2 = (__bf16*)alloc(1024 * 256 * 2);
  __bf16* hwin = (__bf16*)alloc((size_t)NTOK * 256 * 2);  // LN1 out; reused: cm, then y
  __bf16* qkv  = (__bf16*)alloc((size_t)NTOK * 768 * 2);  // qkv; later mlp hidden
  __bf16* owin = (__bf16*)alloc((size_t)NTOK * 256 * 2);  // attn out (follows qkv)
  __bf16* cmb  = hwin;
  __bf16* yb   = hwin;
  __bf16* mlph = qkv;    // 128MB contiguous (qkv+owin)
  float* x2    = (float*)d_out;

  prep_weights<<<3072, 256, 0, stream>>>(qkv_w, proj_w, mlp_w1, mlp_w2,
                                         wt_qkv, wt_proj, wt_mlp1, wt_mlp2);
  ln_kernel<0><<<NTOK / 4, 256, 0, stream>>>(x, n1g, n1b, hwin, 1e-5f);
  gemm_kernel<0><<<(768 / BN) * (NTOK / BM), 256, 0, stream>>>(
      hwin, wt_qkv, qkv_b, nullptr, qkv, NTOK, 768, 256);
  cm_prep<<<8192, 256, 0, stream>>>(rbt, ridx, amask, cmb);
  attn_mfma<<<2048, 256, 0, stream>>>(qkv, cmb, owin);
  gemm_kernel<1><<<(256 / BN) * (NTOK / BM), 256, 0, stream>>>(
      owin, wt_proj, proj_b, x, x2, NTOK, 256, 256);
  ln_kernel<1><<<NTOK / 4, 256, 0, stream>>>(x2, n2g, n2b, yb, 1e-6f);
  gemm_kernel<2><<<(1024 / BN) * (NTOK / BM), 256, 0, stream>>>(
      yb, wt_mlp1, mlp_b1, nullptr, mlph, NTOK, 1024, 256);
  gemm_kernel<3><<<(256 / BN) * (NTOK / BM), 256, 0, stream>>>(
      mlph, wt_mlp2, mlp_b2, x2, d_out, NTOK, 256, 1024);
}

// Round 4
// 303.565 us; speedup vs baseline: 2.4327x; 1.1854x over previous
//
#include <hip/hip_runtime.h>
#include <cstdint>
#include <cstddef>

// ---------- types ----------
typedef float  f32x4_t  __attribute__((ext_vector_type(4)));
typedef __bf16 bf16x8_t __attribute__((ext_vector_type(8)));
typedef __bf16 bf16x4_t __attribute__((ext_vector_type(4)));

#define NTOK   65536   // B*T*H*W = 4*16*32*32
#define CCH    256
#define NWINT  1024    // total windows (B*256)

// ---------- helpers ----------
__device__ __forceinline__ float wred_sum(float v) {
#pragma unroll
  for (int off = 32; off > 0; off >>= 1) v += __shfl_xor(v, off, 64);
  return v;
}

// async global->LDS, 16B per lane; lds dest must be wave-uniform (HW adds lane*16)
__device__ __forceinline__ void gload16(void* lds, const void* g) {
  __builtin_amdgcn_global_load_lds(
      (const __attribute__((address_space(1))) uint32_t*)g,
      (__attribute__((address_space(3))) uint32_t*)lds, 16, 0, 0);
}

// windowed-token -> original-token index (roll shift +2 both directions)
__device__ __forceinline__ int win_to_orig(int token) {
  int gid = token >> 6, n = token & 63;
  int bb = gid >> 8, rem = gid & 255;
  int t = (((rem >> 6) << 2) + (n >> 4) + 2) & 15;
  int h = ((((rem >> 3) & 7) << 2) + ((n >> 2) & 3) + 2) & 31;
  int w = (((rem & 7) << 2) + (n & 3) + 2) & 31;
  return ((bb * 16 + t) * 32 + h) * 32 + w;
}

// ---------- weight transpose + bf16 convert ----------
__global__ __launch_bounds__(256) void prep_weights(
    const float* __restrict__ qkv_w, const float* __restrict__ proj_w,
    const float* __restrict__ mlp_w1, const float* __restrict__ mlp_w2,
    __bf16* __restrict__ wt_qkv, __bf16* __restrict__ wt_proj,
    __bf16* __restrict__ wt_mlp1, __bf16* __restrict__ wt_mlp2) {
  int i = blockIdx.x * 256 + threadIdx.x;
  if (i < 196608) {
    int k = i / 768, n = i % 768;
    wt_qkv[n * 256 + k] = (__bf16)qkv_w[i];
  } else if (i < 262144) {
    int j = i - 196608;
    int k = j >> 8, n = j & 255;
    wt_proj[n * 256 + k] = (__bf16)proj_w[j];
  } else if (i < 524288) {
    int j = i - 262144;
    int k = j >> 10, n = j & 1023;
    wt_mlp1[n * 256 + k] = (__bf16)mlp_w1[j];
  } else {
    int j = i - 524288;
    int k = j >> 8, n = j & 255;
    wt_mlp2[n * 1024 + k] = (__bf16)mlp_w2[j];
  }
}

// ---------- bias+mask precompute, fragment-ordered ----------
__global__ __launch_bounds__(256) void cm_prep(
    const float* __restrict__ table, const int* __restrict__ ridx,
    const float* __restrict__ mask, __bf16* __restrict__ cm) {
  int tid = blockIdx.x * 256 + threadIdx.x;  // 0 .. 2M-1
  int l = tid & 63;
  int t16 = (tid >> 6) & 15;
  int h = (tid >> 10) & 7;
  int w = tid >> 13;  // 0..255
  int it = t16 & 3, jt = t16 >> 2;
  int i = it * 16 + (l & 15);
  int jb = jt * 16 + ((l >> 4) << 2);
  const float* mrow = mask + (size_t)w * 4096 + i * 64;
  const int* rrow = ridx + i * 64;
  bf16x4_t o;
#pragma unroll
  for (int r = 0; r < 4; ++r) {
    int j = jb + r;
    o[r] = (__bf16)(table[rrow[j] * 8 + h] + mrow[j]);
  }
  *(bf16x4_t*)(cm + (size_t)tid * 4) = o;
}

// ---------- LayerNorm (wave per token) ----------
template <int MODE>
__global__ __launch_bounds__(256) void ln_kernel(
    const float* __restrict__ xin, const float* __restrict__ g,
    const float* __restrict__ b, __bf16* __restrict__ out, float eps) {
  int token = blockIdx.x * 4 + (threadIdx.x >> 6);
  int lane = threadIdx.x & 63;
  size_t src = (MODE == 0) ? (size_t)win_to_orig(token) : (size_t)token;
  f32x4_t v = ((const f32x4_t*)(xin + src * CCH))[lane];
  float mu = wred_sum(v[0] + v[1] + v[2] + v[3]) * (1.0f / 256.0f);
  float d0 = v[0] - mu, d1 = v[1] - mu, d2 = v[2] - mu, d3 = v[3] - mu;
  float var = wred_sum(d0 * d0 + d1 * d1 + d2 * d2 + d3 * d3) * (1.0f / 256.0f);
  float rs = rsqrtf(var + eps);
  f32x4_t gg = ((const f32x4_t*)g)[lane];
  f32x4_t bb = ((const f32x4_t*)b)[lane];
  bf16x4_t o;
  o[0] = (__bf16)(d0 * rs * gg[0] + bb[0]);
  o[1] = (__bf16)(d1 * rs * gg[1] + bb[1]);
  o[2] = (__bf16)(d2 * rs * gg[2] + bb[2]);
  o[3] = (__bf16)(d3 * rs * gg[3] + bb[3]);
  *(bf16x4_t*)(out + (size_t)token * CCH + lane * 4) = o;
}

// ---------- GEMM: C = A(bf16 MxK) @ Bt(bf16 NxK)^T + bias ----------
// 128x256 tile, 8 waves (2M x 4N), BK=64, single-buffer LDS (48 KiB),
// hoisted staging pointers, XOR swizzle, bijective XCD-chunked grid swizzle.
#define BMG 128
#define BNG 256
#define BKG 64
template <int EPI>
__global__ __launch_bounds__(512, 4) void gemm_kernel(
    const __bf16* __restrict__ A, const __bf16* __restrict__ Bt,
    const float* __restrict__ bias, const float* __restrict__ res,
    void* __restrict__ outp, int M, int N, int K) {
  __shared__ __bf16 smA[BMG * BKG];  // 16 KB, row stride 64
  __shared__ __bf16 smB[BNG * BKG];  // 32 KB
  const int wv = threadIdx.x >> 6;
  const int ln = threadIdx.x & 63;
  const int i15 = ln & 15, g = ln >> 4;

  // bijective XCD-chunked swizzle (all grids here are %8==0)
  int nwg = gridDim.x;
  int wgid = ((int)blockIdx.x & 7) * (nwg >> 3) + ((int)blockIdx.x >> 3);
  int nx = N >> 8;
  int bx = wgid % nx, by = wgid / nx;
  const int bm = by * BMG, bn = bx * BNG;
  const int wr = wv >> 2, wc = wv & 3;  // 2M x 4N

  // per-lane staging pointers (computed once, bumped per tile)
  const __bf16* aP[2];
  const __bf16* bP[4];
#pragma unroll
  for (int it = 0; it < 2; ++it) {
    int slot = (it * 8 + wv) * 64 + ln;  // 0..1023
    int row = slot >> 3;
    int chunk = (slot & 7) ^ (row & 7);
    aP[it] = A + (size_t)(bm + row) * K + chunk * 8;
  }
#pragma unroll
  for (int it = 0; it < 4; ++it) {
    int slot = (it * 8 + wv) * 64 + ln;  // 0..2047
    int row = slot >> 3;
    int chunk = (slot & 7) ^ (row & 7);
    bP[it] = Bt + (size_t)(bn + row) * K + chunk * 8;
  }

  f32x4_t acc[4][4];
#pragma unroll
  for (int m = 0; m < 4; ++m)
#pragma unroll
    for (int n = 0; n < 4; ++n) acc[m][n] = (f32x4_t){0.f, 0.f, 0.f, 0.f};

  const int KT = K >> 6;
  for (int kt = 0; kt < KT; ++kt) {
    // stage (6 gload16/thread)
#pragma unroll
    for (int it = 0; it < 2; ++it) {
      gload16(&smA[(it * 8 + wv) * 512], aP[it]);
      aP[it] += BKG;
    }
#pragma unroll
    for (int it = 0; it < 4; ++it) {
      gload16(&smB[(it * 8 + wv) * 512], bP[it]);
      bP[it] += BKG;
    }
    asm volatile("s_waitcnt vmcnt(0)" ::: "memory");
    __syncthreads();

#pragma unroll
    for (int kh = 0; kh < 2; ++kh) {
      int co = ((kh * 4 + g) ^ (i15 & 7)) * 8;
      bf16x8_t af[4], bfr[4];
#pragma unroll
      for (int m = 0; m < 4; ++m)
        af[m] = *(const bf16x8_t*)(smA + (wr * 64 + m * 16 + i15) * 64 + co);
#pragma unroll
      for (int n = 0; n < 4; ++n)
        bfr[n] = *(const bf16x8_t*)(smB + (wc * 64 + n * 16 + i15) * 64 + co);
#pragma unroll
      for (int m = 0; m < 4; ++m)
#pragma unroll
        for (int n = 0; n < 4; ++n)
          acc[m][n] = __builtin_amdgcn_mfma_f32_16x16x32_bf16(
              af[m], bfr[n], acc[m][n], 0, 0, 0);
    }
    __syncthreads();  // reads drained (lgkm) before next stage overwrites
  }

  // epilogue: C/D layout col=ln&15, row=(ln>>4)*4+reg
  float bv[4];
#pragma unroll
  for (int n = 0; n < 4; ++n) bv[n] = bias[bn + wc * 64 + n * 16 + i15];
#pragma unroll
  for (int m = 0; m < 4; ++m) {
    int grow0 = bm + wr * 64 + m * 16 + g * 4;
#pragma unroll
    for (int r = 0; r < 4; ++r) {
      int grow = grow0 + r;
      size_t rowbase;
      if constexpr (EPI == 1)
        rowbase = (size_t)win_to_orig(grow) * CCH;
      else
        rowbase = (size_t)grow * N;
#pragma unroll
      for (int n = 0; n < 4; ++n) {
        int gcol = bn + wc * 64 + n * 16 + i15;
        float v = acc[m][n][r] + bv[n];
        if constexpr (EPI == 0) {
          ((__bf16*)outp)[rowbase + gcol] = (__bf16)v;
        } else if constexpr (EPI == 1) {
          size_t dst = rowbase + gcol;
          ((float*)outp)[dst] = res[dst] + v;
        } else if constexpr (EPI == 2) {
          // tanh-GELU (max abs err ~3e-4 vs exact erf form)
          float u = v * (0.7978845608028654f + 0.03567740814f * v * v);
          float t = 1.0f - 2.0f / (__expf(2.0f * u) + 1.0f);
          float gl = 0.5f * v * (1.0f + t);
          ((__bf16*)outp)[rowbase + gcol] = (__bf16)gl;
        } else {
          size_t o = rowbase + gcol;
          ((float*)outp)[o] = res[o] + v;
        }
      }
    }
  }
}

// ---------- MFMA windowed attention: 1 wave per (window, head) ----------
__global__ __launch_bounds__(256) void attn_mfma(
    const __bf16* __restrict__ qkv, const __bf16* __restrict__ cm,
    __bf16* __restrict__ owin) {
  __shared__ __align__(16) __bf16 smP[4][64 * 72];  // P, padded stride 72
  __shared__ __align__(16) __bf16 smV[4][64 * 32];  // V, linear rows
  const int wv = threadIdx.x >> 6;
  const int ln = threadIdx.x & 63;
  const int task = blockIdx.x * 4 + wv;  // 0..8191
  const int win = task >> 3;
  const int h = task & 7;
  const int i15 = ln & 15, g = ln >> 4;

  const __bf16* base = qkv + (size_t)win * 64 * 768 + h * 32;

  // stage V (rows j, 32 d) -> LDS linear, async
  {
    __bf16* vdst = smV[wv];
#pragma unroll
    for (int c = 0; c < 4; ++c) {
      const __bf16* src =
          base + (size_t)(c * 16 + (ln >> 2)) * 768 + 512 + (ln & 3) * 8;
      gload16(vdst + c * 512, src);
    }
  }

  // K/Q fragments straight from global
  bf16x8_t kf[4], qf[4];
#pragma unroll
  for (int t = 0; t < 4; ++t) {
    kf[t] = *(const bf16x8_t*)(base + (size_t)(t * 16 + i15) * 768 + 256 + g * 8);
    qf[t] = *(const bf16x8_t*)(base + (size_t)(t * 16 + i15) * 768 + g * 8);
  }

  // S^T tiles: st[jt][it], rows j, cols i
  f32x4_t st[4][4];
#pragma unroll
  for (int jt = 0; jt < 4; ++jt)
#pragma unroll
    for (int it = 0; it < 4; ++it)
      st[jt][it] = __builtin_amdgcn_mfma_f32_16x16x32_bf16(
          kf[jt], qf[it], (f32x4_t){0.f, 0.f, 0.f, 0.f}, 0, 0, 0);

  // scale + bias + mask (fragment-ordered cm)
  const __bf16* cmp = cm + (((size_t)(win & 255) * 8 + h) * 16) * 256;
#pragma unroll
  for (int jt = 0; jt < 4; ++jt)
#pragma unroll
    for (int it = 0; it < 4; ++it) {
      bf16x4_t c4 = *(const bf16x4_t*)(cmp + ((jt * 4 + it) * 64 + ln) * 4);
#pragma unroll
      for (int r = 0; r < 4; ++r)
        st[jt][it][r] =
            fmaf(st[jt][it][r], 0.17677669529663687f, (float)c4[r]);
    }

  // softmax over j per column i
#pragma unroll
  for (int it = 0; it < 4; ++it) {
    float mx = -1e30f;
#pragma unroll
    for (int jt = 0; jt < 4; ++jt)
#pragma unroll
      for (int r = 0; r < 4; ++r) mx = fmaxf(mx, st[jt][it][r]);
    mx = fmaxf(mx, __shfl_xor(mx, 16, 64));
    mx = fmaxf(mx, __shfl_xor(mx, 32, 64));
    float sum = 0.f;
#pragma unroll
    for (int jt = 0; jt < 4; ++jt)
#pragma unroll
      for (int r = 0; r < 4; ++r) {
        float p = __expf(st[jt][it][r] - mx);
        st[jt][it][r] = p;
        sum += p;
      }
    sum += __shfl_xor(sum, 16, 64);
    sum += __shfl_xor(sum, 32, 64);
    float inv = 1.0f / sum;
#pragma unroll
    for (int jt = 0; jt < 4; ++jt) {
      bf16x4_t p4;
#pragma unroll
      for (int r = 0; r < 4; ++r) p4[r] = (__bf16)(st[jt][it][r] * inv);
      *(bf16x4_t*)(smP[wv] + (it * 16 + i15) * 72 + jt * 16 + g * 4) = p4;
    }
  }
  __syncthreads();  // drain V gload (vmcnt) + P writes (lgkm)

  // O = P @ V
  f32x4_t oacc[4][2];
#pragma unroll
  for (int it = 0; it < 4; ++it)
#pragma unroll
    for (int dt = 0; dt < 2; ++dt) oacc[it][dt] = (f32x4_t){0.f, 0.f, 0.f, 0.f};

  const __bf16* pl = smP[wv];
  const __bf16* vl = smV[wv];
#pragma unroll
  for (int kt = 0; kt < 2; ++kt) {
    bf16x8_t vf[2];
#pragma unroll
    for (int dt = 0; dt < 2; ++dt)
#pragma unroll
      for (int e = 0; e < 8; ++e)
        vf[dt][e] = vl[(kt * 32 + g * 8 + e) * 32 + dt * 16 + i15];
#pragma unroll
    for (int it = 0; it < 4; ++it) {
      bf16x8_t pa =
          *(const bf16x8_t*)(pl + (it * 16 + i15) * 72 + kt * 32 + g * 8);
#pragma unroll
      for (int dt = 0; dt < 2; ++dt)
        oacc[it][dt] = __builtin_amdgcn_mfma_f32_16x16x32_bf16(
            pa, vf[dt], oacc[it][dt], 0, 0, 0);
    }
  }

  __bf16* op = owin + (size_t)win * 64 * 256 + h * 32;
#pragma unroll
  for (int it = 0; it < 4; ++it)
#pragma unroll
    for (int r = 0; r < 4; ++r) {
      int i = it * 16 + g * 4 + r;
#pragma unroll
      for (int dt = 0; dt < 2; ++dt)
        op[(size_t)i * 256 + dt * 16 + i15] = (__bf16)oacc[it][dt][r];
    }
}

// ---------- launch ----------
extern "C" void kernel_launch(void* const* d_in, const int* in_sizes, int n_in,
                              void* d_out, int out_size, void* d_ws,
                              size_t ws_size, hipStream_t stream) {
  (void)in_sizes; (void)n_in; (void)out_size; (void)ws_size;
  const float* x      = (const float*)d_in[0];
  const float* n1g    = (const float*)d_in[1];
  const float* n1b    = (const float*)d_in[2];
  const float* qkv_w  = (const float*)d_in[3];
  const float* qkv_b  = (const float*)d_in[4];
  const float* proj_w = (const float*)d_in[5];
  const float* proj_b = (const float*)d_in[6];
  const float* rbt    = (const float*)d_in[7];
  const float* n2g    = (const float*)d_in[8];
  const float* n2b    = (const float*)d_in[9];
  const float* mlp_w1 = (const float*)d_in[10];
  const float* mlp_b1 = (const float*)d_in[11];
  const float* mlp_w2 = (const float*)d_in[12];
  const float* mlp_b2 = (const float*)d_in[13];
  const int*   ridx   = (const int*)d_in[14];
  const float* amask  = (const float*)d_in[15];

  char* ws = (char*)d_ws;
  size_t off = 0;
  auto alloc = [&](size_t bytes) {
    void* p = ws + off;
    off += (bytes + 255) & ~(size_t)255;
    return p;
  };
  __bf16* wt_qkv  = (__bf16*)alloc(768 * 256 * 2);
  __bf16* wt_proj = (__bf16*)alloc(256 * 256 * 2);
  __bf16* wt_mlp1 = (__bf16*)alloc(1024 * 256 * 2);
  __bf16* wt_mlp2 = (__bf16*)alloc(1024 * 256 * 2);
  __bf16* hwin = (__bf16*)alloc((size_t)NTOK * 256 * 2);  // LN1 out; reused: cm, then y
  __bf16* qkv  = (__bf16*)alloc((size_t)NTOK * 768 * 2);  // qkv; later mlp hidden
  __bf16* owin = (__bf16*)alloc((size_t)NTOK * 256 * 2);  // attn out (follows qkv)
  __bf16* cmb  = hwin;
  __bf16* yb   = hwin;
  __bf16* mlph = qkv;    // 128MB contiguous (qkv+owin)
  float* x2    = (float*)d_out;

  prep_weights<<<3072, 256, 0, stream>>>(qkv_w, proj_w, mlp_w1, mlp_w2,
                                         wt_qkv, wt_proj, wt_mlp1, wt_mlp2);
  ln_kernel<0><<<NTOK / 4, 256, 0, stream>>>(x, n1g, n1b, hwin, 1e-5f);
  gemm_kernel<0><<<(768 / BNG) * (NTOK / BMG), 512, 0, stream>>>(
      hwin, wt_qkv, qkv_b, nullptr, qkv, NTOK, 768, 256);
  cm_prep<<<8192, 256, 0, stream>>>(rbt, ridx, amask, cmb);
  attn_mfma<<<2048, 256, 0, stream>>>(qkv, cmb, owin);
  gemm_kernel<1><<<(256 / BNG) * (NTOK / BMG), 512, 0, stream>>>(
      owin, wt_proj, proj_b, x, x2, NTOK, 256, 256);
  ln_kernel<1><<<NTOK / 4, 256, 0, stream>>>(x2, n2g, n2b, yb, 1e-6f);
  gemm_kernel<2><<<(1024 / BNG) * (NTOK / BMG), 512, 0, stream>>>(
      yb, wt_mlp1, mlp_b1, nullptr, mlph, NTOK, 1024, 256);
  gemm_kernel<3><<<(256 / BNG) * (NTOK / BMG), 512, 0, stream>>>(
      mlph, wt_mlp2, mlp_b2, x2, d_out, NTOK, 256, 1024);
}